// Round 1
// baseline (186.796 us; speedup 1.0000x reference)
//
#include <hip/hip_runtime.h>

// RBF classifier: out = exp(-(||x-c||^2) * exp(-2*log_sigma)) @ W^T + b
// B=16384, D=784, C=2048, OUT=10. All fp32 in/out.
//
// Strategy: bf16 MFMA for the (B,D)x(D,C) dot GEMM via the identity
// d2 = x2 + c2 - 2*x.c ; fused epilogue computes phi and a per-block
// 128x10 mini-GEMM vs W, accumulated into out with fp32 atomics.
// K padded 784->800 so BK=32 divides (pad region zeros => no-op).

#define B_ROWS 16384
#define D_DIM  784
#define C_DIM  2048
#define NOUT   10
#define KPAD   800

typedef __attribute__((ext_vector_type(8))) __bf16 bf16x8;
typedef __attribute__((ext_vector_type(4))) float  f32x4;
typedef __attribute__((ext_vector_type(4))) unsigned short ushort4v;

__device__ __forceinline__ unsigned short f2bf(float f) {
  union { float f; unsigned int u; } v; v.f = f;
  unsigned int u = v.u;
  return (unsigned short)((u + 0x7fffu + ((u >> 16) & 1u)) >> 16);  // RNE
}

// async global->LDS, 16B per lane. LDS dest = wave-uniform base + lane*16.
__device__ __forceinline__ void async16(const unsigned short* g, unsigned short* l) {
  __builtin_amdgcn_global_load_lds((const __attribute__((address_space(1))) void*)g,
                                   (__attribute__((address_space(3))) void*)l,
                                   16, 0, 0);
}

// --- prep: fp32 row -> bf16 row (padded to KPAD with zeros) + sum of squares.
// one block (256 thr) per row; 784 = 196 float4.
__global__ __launch_bounds__(256) void prep_rows(const float* __restrict__ src,
                                                 unsigned short* __restrict__ dst,
                                                 float* __restrict__ sq) {
  const int row = blockIdx.x;
  const int t = threadIdx.x;
  float s = 0.f;
  if (t < 196) {
    const float4 v = ((const float4*)(src + (size_t)row * D_DIM))[t];
    ushort4v o; o.x = f2bf(v.x); o.y = f2bf(v.y); o.z = f2bf(v.z); o.w = f2bf(v.w);
    *(ushort4v*)(dst + (size_t)row * KPAD + t * 4) = o;
    s = v.x * v.x + v.y * v.y + v.z * v.z + v.w * v.w;
  } else if (t < 200) {  // zero-pad k = 784..799
    ushort4v z = {0, 0, 0, 0};
    *(ushort4v*)(dst + (size_t)row * KPAD + t * 4) = z;
  }
  for (int off = 32; off > 0; off >>= 1) s += __shfl_down(s, off);
  __shared__ float red[4];
  if ((t & 63) == 0) red[t >> 6] = s;
  __syncthreads();
  if (t == 0) sq[row] = red[0] + red[1] + red[2] + red[3];
}

__global__ __launch_bounds__(256) void prep_scale(const float* __restrict__ ls,
                                                  float* __restrict__ scale) {
  const int i = blockIdx.x * 256 + threadIdx.x;
  if (i < C_DIM) scale[i] = __expf(-2.f * ls[i]);
}

// W (10,2048) fp32 -> Wb (16,2048) bf16, rows 10..15 zero.
__global__ __launch_bounds__(256) void prep_w(const float* __restrict__ W,
                                              unsigned short* __restrict__ wb) {
  const int i = blockIdx.x * 256 + threadIdx.x;  // 16*2048 = 32768
  const int o = i >> 11, c = i & 2047;
  wb[i] = (o < NOUT) ? f2bf(W[o * C_DIM + c]) : (unsigned short)0;
}

// out[b][o] = bias[o]
__global__ __launch_bounds__(256) void init_out(const float* __restrict__ bias,
                                                float* __restrict__ out) {
  const int i = blockIdx.x * 256 + threadIdx.x;  // 163840
  out[i] = bias[i % NOUT];
}

// --- main fused kernel: 128x128 tile over (B,C), BK=32, 4 waves 2x2.
__global__ __launch_bounds__(256, 2) void rbf_main(
    const unsigned short* __restrict__ xb, const unsigned short* __restrict__ cb,
    const unsigned short* __restrict__ wb,
    const float* __restrict__ x2, const float* __restrict__ c2,
    const float* __restrict__ scale, float* __restrict__ out) {
  __shared__ unsigned short As[128 * 32];    // 8 KB, row-major [row][k], no pad (global_load_lds)
  __shared__ unsigned short Bs[128 * 32];    // 8 KB
  __shared__ unsigned short Ph[128 * 136];   // 34 KB phi tile, +8 pad keeps 16B align
  __shared__ float x2s[128], c2s[128], scs[128];

  const int tid  = threadIdx.x;
  const int w    = tid >> 6;
  const int lane = tid & 63;
  const int q    = lane >> 4;
  const int l16  = lane & 15;
  const int brow = blockIdx.x * 128;
  const int bcol = blockIdx.y * 128;

  if (tid < 128) x2s[tid] = x2[brow + tid];
  else { c2s[tid - 128] = c2[bcol + tid - 128]; scs[tid - 128] = scale[bcol + tid - 128]; }

  // staging map: thread t covers (row = t/4 [+64 on 2nd issue], k = (t&3)*8..+8)
  const int arow = tid >> 2;
  const int akb  = (tid & 3) * 8;
  const unsigned short* gA = xb + (size_t)(brow + arow) * KPAD + akb;
  const unsigned short* gB = cb + (size_t)(bcol + arow) * KPAD + akb;
  unsigned short* lA0 = &As[w * 512];
  unsigned short* lA1 = &As[2048 + w * 512];
  unsigned short* lB0 = &Bs[w * 512];
  unsigned short* lB1 = &Bs[2048 + w * 512];

  const int wr = (w >> 1) * 64;  // wave row offset in tile
  const int wc = (w & 1) * 64;   // wave col offset

  f32x4 acc[4][4] = {};

  for (int k0 = 0; k0 < KPAD; k0 += 32) {
    async16(gA + k0, lA0);
    async16(gA + (size_t)64 * KPAD + k0, lA1);
    async16(gB + k0, lB0);
    async16(gB + (size_t)64 * KPAD + k0, lB1);
    __syncthreads();  // drains vmcnt (global_load_lds) per barrier semantics
    bf16x8 af[4], bfr[4];
#pragma unroll
    for (int i = 0; i < 4; ++i)
      af[i] = *(const bf16x8*)&As[(wr + i * 16 + l16) * 32 + q * 8];
#pragma unroll
    for (int j = 0; j < 4; ++j)
      bfr[j] = *(const bf16x8*)&Bs[(wc + j * 16 + l16) * 32 + q * 8];
#pragma unroll
    for (int i = 0; i < 4; ++i)
#pragma unroll
      for (int j = 0; j < 4; ++j)
        acc[i][j] = __builtin_amdgcn_mfma_f32_16x16x32_bf16(af[i], bfr[j], acc[i][j], 0, 0, 0);
    __syncthreads();
  }

  // epilogue 1: d2 -> phi -> Ph (bf16). C/D layout: col=lane&15, row=q*4+r.
#pragma unroll
  for (int i = 0; i < 4; ++i) {
#pragma unroll
    for (int j = 0; j < 4; ++j) {
      const int cl = wc + j * 16 + l16;
      const float c2v = c2s[cl];
      const float sc = scs[cl];
#pragma unroll
      for (int r = 0; r < 4; ++r) {
        const int rl = wr + i * 16 + q * 4 + r;
        float d2 = x2s[rl] + c2v - 2.f * acc[i][j][r];
        d2 = fmaxf(d2, 0.f);
        const float phi = __expf(-d2 * sc);
        Ph[rl * 136 + cl] = f2bf(phi);
      }
    }
  }
  __syncthreads();

  // epilogue 2: out_tile(128x10) = Ph(128x128) @ Wb(16x128 slice)^T, K=128.
  // wave w handles rows w*32 .. w*32+31 (2 M-frags).
  f32x4 oacc[2] = {};
#pragma unroll
  for (int kk = 0; kk < 4; ++kk) {
    const bf16x8 bw = *(const bf16x8*)&wb[(size_t)l16 * C_DIM + bcol + kk * 32 + q * 8];
#pragma unroll
    for (int mi = 0; mi < 2; ++mi) {
      const bf16x8 ap = *(const bf16x8*)&Ph[(w * 32 + mi * 16 + l16) * 136 + kk * 32 + q * 8];
      oacc[mi] = __builtin_amdgcn_mfma_f32_16x16x32_bf16(ap, bw, oacc[mi], 0, 0, 0);
    }
  }
  if (l16 < NOUT) {
#pragma unroll
    for (int mi = 0; mi < 2; ++mi)
#pragma unroll
      for (int r = 0; r < 4; ++r) {
        const int grow = brow + w * 32 + mi * 16 + q * 4 + r;
        atomicAdd(&out[grow * NOUT + l16], oacc[mi][r]);
      }
  }
}

extern "C" void kernel_launch(void* const* d_in, const int* in_sizes, int n_in,
                              void* d_out, int out_size, void* d_ws, size_t ws_size,
                              hipStream_t stream) {
  const float* x    = (const float*)d_in[0];  // (16384,784)
  const float* cen  = (const float*)d_in[1];  // (2048,784)
  const float* ls   = (const float*)d_in[2];  // (2048,)
  const float* W    = (const float*)d_in[3];  // (10,2048)
  const float* bias = (const float*)d_in[4];  // (10,)
  float* out = (float*)d_out;                 // (16384,10)

  unsigned char* ws = (unsigned char*)d_ws;
  unsigned short* xb  = (unsigned short*)(ws);              // 16384*800*2 = 26,214,400
  unsigned short* cbf = (unsigned short*)(ws + 26214400);   //  2048*800*2 =  3,276,800
  unsigned short* wb  = (unsigned short*)(ws + 29491200);   //    16*2048*2 =    65,536
  float* x2 = (float*)(ws + 29556736);                      // 16384*4
  float* c2 = (float*)(ws + 29622272);                      //  2048*4
  float* sc = (float*)(ws + 29630464);                      //  2048*4   (end 29,638,656)

  prep_rows<<<B_ROWS, 256, 0, stream>>>(x, xb, x2);
  prep_rows<<<C_DIM, 256, 0, stream>>>(cen, cbf, c2);
  prep_scale<<<(C_DIM + 255) / 256, 256, 0, stream>>>(ls, sc);
  prep_w<<<(16 * C_DIM) / 256, 256, 0, stream>>>(W, wb);
  init_out<<<(B_ROWS * NOUT) / 256, 256, 0, stream>>>(bias, out);
  rbf_main<<<dim3(B_ROWS / 128, C_DIM / 128), 256, 0, stream>>>(xb, cbf, wb, x2, c2, sc, out);
}

// Round 2
// 163.908 us; speedup vs baseline: 1.1396x; 1.1396x over previous
//
#include <hip/hip_runtime.h>

// RBF classifier: out = exp(-(||x-c||^2) * exp(-2*log_sigma)) @ W^T + b
// B=16384, D=784, C=2048, OUT=10. All fp32 in/out.
//
// R2: union LDS (Ph overlays As/Bs stage: 52.7KB -> 36.3KB => 4 blocks/CU),
// BK 32->64 (half the barriers) with XOR bank swizzle, fused small preps,
// wave-per-row prep_rows. K padded 784->832 (13 x 64).

#define B_ROWS 16384
#define D_DIM  784
#define C_DIM  2048
#define NOUT   10
#define KPAD   832
#define BK     64

typedef __attribute__((ext_vector_type(8))) __bf16 bf16x8;
typedef __attribute__((ext_vector_type(4))) float  f32x4;
typedef __attribute__((ext_vector_type(4))) unsigned short ushort4v;

__device__ __forceinline__ unsigned short f2bf(float f) {
  union { float f; unsigned int u; } v; v.f = f;
  unsigned int u = v.u;
  return (unsigned short)((u + 0x7fffu + ((u >> 16) & 1u)) >> 16);  // RNE
}

// async global->LDS, 16B per lane. LDS dest = wave-uniform base + lane*16.
__device__ __forceinline__ void async16(const unsigned short* g, unsigned short* l) {
  __builtin_amdgcn_global_load_lds((const __attribute__((address_space(1))) void*)g,
                                   (__attribute__((address_space(3))) void*)l,
                                   16, 0, 0);
}

// --- prep: fp32 row -> bf16 row (padded to KPAD zeros) + sum of squares.
// one WAVE per row (4 rows / 256-thr block); no LDS, no syncthreads.
__global__ __launch_bounds__(256) void prep_rows(const float* __restrict__ src,
                                                 unsigned short* __restrict__ dst,
                                                 float* __restrict__ sq) {
  const int row  = blockIdx.x * 4 + (threadIdx.x >> 6);
  const int lane = threadIdx.x & 63;
  const float* s = src + (size_t)row * D_DIM;
  unsigned short* d = dst + (size_t)row * KPAD;
  float acc = 0.f;
#pragma unroll
  for (int c = 0; c < 4; ++c) {
    const int ch = lane + c * 64;           // ushort4 chunk index, 208 total
    if (ch < 196) {
      const float4 v = ((const float4*)s)[ch];
      ushort4v o; o.x = f2bf(v.x); o.y = f2bf(v.y); o.z = f2bf(v.z); o.w = f2bf(v.w);
      *(ushort4v*)(d + ch * 4) = o;
      acc += v.x * v.x + v.y * v.y + v.z * v.z + v.w * v.w;
    } else if (ch < 208) {
      ushort4v z = {0, 0, 0, 0};
      *(ushort4v*)(d + ch * 4) = z;
    }
  }
#pragma unroll
  for (int off = 32; off > 0; off >>= 1) acc += __shfl_down(acc, off);
  if (lane == 0) sq[row] = acc;
}

// fused tiny preps: out=bias | Wb bf16 (16,2048; rows 10..15 zero) | scale.
__global__ __launch_bounds__(256) void prep_misc(const float* __restrict__ ls,
                                                 const float* __restrict__ W,
                                                 const float* __restrict__ bias,
                                                 float* __restrict__ scale,
                                                 unsigned short* __restrict__ wb,
                                                 float* __restrict__ out) {
  const int i = blockIdx.x * 256 + threadIdx.x;
  if (i < B_ROWS * NOUT) out[i] = bias[i % NOUT];
  const int j = i - B_ROWS * NOUT;
  if (j >= 0 && j < 16 * C_DIM)
    wb[j] = ((j >> 11) < NOUT) ? f2bf(W[(j >> 11) * C_DIM + (j & 2047)]) : (unsigned short)0;
  const int k = j - 16 * C_DIM;
  if (k >= 0 && k < C_DIM) scale[k] = __expf(-2.f * ls[k]);
}

// --- main fused kernel: 128x128 tile over (B,C), BK=64, 4 waves 2x2.
// LDS union: [ As(16K) | Bs(16K) ] overlaid by Ph(34K); + 1.5K f32 vectors.
__global__ __launch_bounds__(256, 4) void rbf_main(
    const unsigned short* __restrict__ xb, const unsigned short* __restrict__ cb,
    const unsigned short* __restrict__ wb,
    const float* __restrict__ x2, const float* __restrict__ c2,
    const float* __restrict__ scale, float* __restrict__ out) {
  __shared__ char smem[34816];               // max(32768 stage, 34816 Ph)
  unsigned short* As = (unsigned short*)smem;            // 128 x 64 shorts
  unsigned short* Bs = (unsigned short*)(smem + 16384);  // 128 x 64 shorts
  unsigned short* Ph = (unsigned short*)smem;            // 128 x 136 shorts
  __shared__ float x2s[128], c2s[128], scs[128];

  const int tid  = threadIdx.x;
  const int w    = tid >> 6;
  const int lane = tid & 63;
  const int q    = lane >> 4;
  const int l16  = lane & 15;
  const int brow = blockIdx.x * 128;
  const int bcol = blockIdx.y * 128;

  if (tid < 128) x2s[tid] = x2[brow + tid];
  else { c2s[tid - 128] = c2[bcol + tid - 128]; scs[tid - 128] = scale[bcol + tid - 128]; }

  // staging: thread t covers (row = r*32 + t/8, k-chunk = (t&7) ^ (row&7)) per
  // issue r. XOR swizzle keeps read side conflict-even at 128B row stride.
  const int srow = tid >> 3;                       // 0..31
  const int skc  = (tid & 7) ^ (srow & 7);         // swizzled k-chunk
  const unsigned short* gA = xb + (size_t)(brow + srow) * KPAD + skc * 8;
  const unsigned short* gB = cb + (size_t)(bcol + srow) * KPAD + skc * 8;
  unsigned short* lA = &As[w * 512];               // + r*2048 per issue
  unsigned short* lB = &Bs[w * 512];

  const int wr = (w >> 1) * 64;  // wave row offset in tile
  const int wc = (w & 1) * 64;   // wave col offset
  const int swz = l16 & 7;

  f32x4 acc[4][4] = {};

  for (int k0 = 0; k0 < KPAD; k0 += BK) {
#pragma unroll
    for (int r = 0; r < 4; ++r) {
      async16(gA + (size_t)r * 32 * KPAD + k0, lA + r * 2048);
      async16(gB + (size_t)r * 32 * KPAD + k0, lB + r * 2048);
    }
    __syncthreads();  // drains vmcnt (global_load_lds) per barrier semantics
#pragma unroll
    for (int ks = 0; ks < 2; ++ks) {
      bf16x8 af[4], bfr[4];
#pragma unroll
      for (int i = 0; i < 4; ++i)
        af[i] = *(const bf16x8*)&As[(wr + i * 16 + l16) * 64 + (((ks * 4 + q) ^ swz) << 3)];
#pragma unroll
      for (int j = 0; j < 4; ++j)
        bfr[j] = *(const bf16x8*)&Bs[(wc + j * 16 + l16) * 64 + (((ks * 4 + q) ^ swz) << 3)];
#pragma unroll
      for (int i = 0; i < 4; ++i)
#pragma unroll
        for (int j = 0; j < 4; ++j)
          acc[i][j] = __builtin_amdgcn_mfma_f32_16x16x32_bf16(af[i], bfr[j], acc[i][j], 0, 0, 0);
    }
    __syncthreads();
  }

  // epilogue 1: d2 -> phi -> Ph (bf16), overlaying the dead stage buffers.
  // C/D layout: col=lane&15, row=q*4+r.
#pragma unroll
  for (int i = 0; i < 4; ++i) {
#pragma unroll
    for (int j = 0; j < 4; ++j) {
      const int cl = wc + j * 16 + l16;
      const float c2v = c2s[cl];
      const float sc = scs[cl];
#pragma unroll
      for (int r = 0; r < 4; ++r) {
        const int rl = wr + i * 16 + q * 4 + r;
        float d2 = x2s[rl] + c2v - 2.f * acc[i][j][r];
        d2 = fmaxf(d2, 0.f);
        const float phi = __expf(-d2 * sc);
        Ph[rl * 136 + cl] = f2bf(phi);
      }
    }
  }
  __syncthreads();

  // epilogue 2: out_tile(128x10) = Ph(128x128) @ Wb(16-row slice)^T, K=128.
  // wave w handles rows w*32 .. w*32+31 (2 M-frags).
  f32x4 oacc[2] = {};
#pragma unroll
  for (int kk = 0; kk < 4; ++kk) {
    const bf16x8 bw = *(const bf16x8*)&wb[(size_t)l16 * C_DIM + bcol + kk * 32 + q * 8];
#pragma unroll
    for (int mi = 0; mi < 2; ++mi) {
      const bf16x8 ap = *(const bf16x8*)&Ph[(w * 32 + mi * 16 + l16) * 136 + kk * 32 + q * 8];
      oacc[mi] = __builtin_amdgcn_mfma_f32_16x16x32_bf16(ap, bw, oacc[mi], 0, 0, 0);
    }
  }
  if (l16 < NOUT) {
#pragma unroll
    for (int mi = 0; mi < 2; ++mi)
#pragma unroll
      for (int r = 0; r < 4; ++r) {
        const int grow = brow + w * 32 + mi * 16 + q * 4 + r;
        atomicAdd(&out[grow * NOUT + l16], oacc[mi][r]);
      }
  }
}

extern "C" void kernel_launch(void* const* d_in, const int* in_sizes, int n_in,
                              void* d_out, int out_size, void* d_ws, size_t ws_size,
                              hipStream_t stream) {
  const float* x    = (const float*)d_in[0];  // (16384,784)
  const float* cen  = (const float*)d_in[1];  // (2048,784)
  const float* ls   = (const float*)d_in[2];  // (2048,)
  const float* W    = (const float*)d_in[3];  // (10,2048)
  const float* bias = (const float*)d_in[4];  // (10,)
  float* out = (float*)d_out;                 // (16384,10)

  unsigned char* ws = (unsigned char*)d_ws;
  unsigned short* xb  = (unsigned short*)(ws);              // 16384*832*2 = 27,262,976
  unsigned short* cbf = (unsigned short*)(ws + 27262976);   //  2048*832*2 =  3,407,872
  unsigned short* wb  = (unsigned short*)(ws + 30670848);   //   16*2048*2 =     65,536
  float* x2 = (float*)(ws + 30736384);                      // 16384*4
  float* c2 = (float*)(ws + 30801920);                      //  2048*4
  float* sc = (float*)(ws + 30810112);                      //  2048*4   (end 30,818,304)

  prep_rows<<<B_ROWS / 4, 256, 0, stream>>>(x, xb, x2);
  prep_rows<<<C_DIM / 4, 256, 0, stream>>>(cen, cbf, c2);
  prep_misc<<<(B_ROWS * NOUT + 16 * C_DIM + C_DIM + 255) / 256, 256, 0, stream>>>(
      ls, W, bias, sc, wb, out);
  rbf_main<<<dim3(B_ROWS / 128, C_DIM / 128), 256, 0, stream>>>(xb, cbf, wb, x2, c2, sc, out);
}